// Round 2
// baseline (6102.069 us; speedup 1.0000x reference)
//
#include <hip/hip_runtime.h>

#define N_    128
#define T_    64
#define D_    512
#define H_    1280
#define FOURH 5120
#define K3    3072           // h(1280) + attn(1280) + x(512)
#define NSTRIP 80            // 5120 / 64 cols per strip
#define KSPLIT 3
#define KCH   1024           // 3072 / 3
#define NBLOCKS (NSTRIP * KSPLIT)
#define BSLICE 65536         // halfs per block weight slice: 64 cols * 1024 k

typedef _Float16 half8 __attribute__((ext_vector_type(8)));
typedef float    f32x4 __attribute__((ext_vector_type(4)));

__device__ __forceinline__ float sigf(float x) { return 1.0f / (1.0f + expf(-x)); }

// ---------------- hand-rolled grid barrier (monotonic counter) ----------------
__device__ __forceinline__ void gbar(unsigned* cnt, unsigned target) {
  __syncthreads();
  if (threadIdx.x == 0) {
    __threadfence();  // device-scope release of this block's writes
    __hip_atomic_fetch_add(cnt, 1u, __ATOMIC_RELEASE, __HIP_MEMORY_SCOPE_AGENT);
    while (__hip_atomic_load(cnt, __ATOMIC_ACQUIRE, __HIP_MEMORY_SCOPE_AGENT) < target)
      __builtin_amdgcn_s_sleep(1);
    __threadfence();  // acquire: invalidate stale L1/L2 lines
  }
  __syncthreads();
}

// ---------------- one-time prep kernels ----------------

// Build per-block LDS images of the fused weight matrix, XOR-swizzled so the
// sequential kernel can stage linearly and ds_read_b128 conflict-free.
// Block b (strip = b%NSTRIP, kc = b/NSTRIP) owns cols [strip*64, +64), k [kc*1024, +1024).
// Element (cl, kk) -> W2ld[b*BSLICE + ((cl*1024 + kk) ^ ((cl&7)*8))]
__global__ __launch_bounds__(256) void build_w2ld(const float* __restrict__ Wh,
                                                  const float* __restrict__ Wa,
                                                  const float* __restrict__ Wx,
                                                  _Float16* __restrict__ W2ld) {
  int bid = blockIdx.x;
  int strip = bid % NSTRIP, kc = bid / NSTRIP;
  int cc0 = strip * 64, k0 = kc * KCH;
  _Float16* dst = W2ld + (size_t)bid * BSLICE;
  int cl = threadIdx.x & 63;
  int kq = threadIdx.x >> 6;          // 4 k-quarters of 256
  for (int kk = kq * 256; kk < kq * 256 + 256; ++kk) {
    int k = k0 + kk;
    int col = cc0 + cl;
    float v;
    if (k < H_)          v = Wh[(size_t)k * FOURH + col];
    else if (k < 2 * H_) v = Wa[(size_t)(k - H_) * FOURH + col];
    else                 v = Wx[(size_t)(k - 2 * H_) * FOURH + col];
    dst[(cl * 1024 + kk) ^ ((cl & 7) * 8)] = (_Float16)v;
  }
}

__global__ __launch_bounds__(256) void cvt_f16(const float* __restrict__ src,
                                               _Float16* __restrict__ dst, int n) {
  for (int i = blockIdx.x * blockDim.x + threadIdx.x; i < n; i += gridDim.x * blockDim.x)
    dst[i] = (_Float16)src[i];
}

// ---------------- attention helper ----------------
__device__ __forceinline__ void attn_and_x(int n, int tnext, int tid,
                                           const float* __restrict__ h_sh,
                                           float (*red)[16], float* w_sh,
                                           const _Float16* __restrict__ Af16,
                                           const _Float16* __restrict__ x16,
                                           _Float16* __restrict__ Aop) {
  const _Float16* Afn = Af16 + (size_t)n * H_ * 16;
  float s[16];
#pragma unroll
  for (int l = 0; l < 16; ++l) s[l] = 0.f;
  for (int hh = tid; hh < H_; hh += 256) {
    float hv = h_sh[hh];
    const half8* af8 = (const half8*)(Afn + (size_t)hh * 16);
    half8 v0 = af8[0], v1 = af8[1];
#pragma unroll
    for (int l = 0; l < 8; ++l) s[l]     += hv * (float)v0[l];
#pragma unroll
    for (int l = 0; l < 8; ++l) s[8 + l] += hv * (float)v1[l];
  }
#pragma unroll
  for (int l = 0; l < 16; ++l) {
#pragma unroll
    for (int off = 32; off > 0; off >>= 1) s[l] += __shfl_down(s[l], off);
  }
  int lane = tid & 63, wv = tid >> 6;
  if (lane == 0) {
#pragma unroll
    for (int l = 0; l < 16; ++l) red[wv][l] = s[l];
  }
  __syncthreads();
  if (tid == 0) {
    const float scale = 0.02795084972579479f;  // 1/sqrt(1280)
    float sc[16], m = -1e30f;
#pragma unroll
    for (int l = 0; l < 16; ++l) {
      sc[l] = scale * (red[0][l] + red[1][l] + red[2][l] + red[3][l]);
      m = fmaxf(m, sc[l]);
    }
    float ssum = 0.f;
#pragma unroll
    for (int l = 0; l < 16; ++l) { sc[l] = expf(sc[l] - m); ssum += sc[l]; }
    float inv = 1.0f / ssum;
#pragma unroll
    for (int l = 0; l < 16; ++l) w_sh[l] = sc[l] * inv;
  }
  __syncthreads();
  _Float16* Aopn = Aop + (size_t)n * K3;
  for (int hh = tid; hh < H_; hh += 256) {
    const half8* af8 = (const half8*)(Afn + (size_t)hh * 16);
    half8 v0 = af8[0], v1 = af8[1];
    float at = 0.f;
#pragma unroll
    for (int l = 0; l < 8; ++l) at += w_sh[l]     * (float)v0[l];
#pragma unroll
    for (int l = 0; l < 8; ++l) at += w_sh[8 + l] * (float)v1[l];
    Aopn[H_ + hh] = (_Float16)at;
  }
  const _Float16* xs = x16 + ((size_t)n * T_ + tnext) * D_;
  for (int j = tid; j < D_; j += 256) Aopn[2 * H_ + j] = xs[j];
}

// ---------------- init: h0 = mean(Af), c0 = h0, attention for step 0 ----------------
__global__ __launch_bounds__(256) void init_state(const float* __restrict__ A,
                                                  const _Float16* __restrict__ Af16,
                                                  const _Float16* __restrict__ x16,
                                                  float* __restrict__ c,
                                                  _Float16* __restrict__ Aop) {
  __shared__ float h_sh[H_];
  __shared__ float red[4][16];
  __shared__ float w_sh[16];
  int n = blockIdx.x, tid = threadIdx.x;
  const float* Afn = A + (size_t)n * H_ * 16;
  _Float16* Aopn = Aop + (size_t)n * K3;
  for (int hh = tid; hh < H_; hh += 256) {
    const float* af = Afn + (size_t)hh * 16;
    float s = 0.f;
#pragma unroll
    for (int l = 0; l < 16; ++l) s += af[l];
    s *= (1.0f / 16.0f);
    c[(size_t)n * H_ + hh] = s;
    h_sh[hh] = s;
    Aopn[hh] = (_Float16)s;
  }
  __syncthreads();
  attn_and_x(n, 0, tid, h_sh, red, w_sh, Af16, x16, Aop);
}

// ---------------- the sequential recurrence (cooperative, weights LDS-resident) ----------------
__global__ __launch_bounds__(256) void seq_kernel(const _Float16* __restrict__ W2ld,
                                                  const _Float16* __restrict__ x16,
                                                  const _Float16* __restrict__ Af16,
                                                  const float* __restrict__ b,
                                                  float* __restrict__ c,
                                                  _Float16* __restrict__ Aop,
                                                  float* __restrict__ P,
                                                  float* __restrict__ out,
                                                  unsigned* __restrict__ bar) {
  __shared__ _Float16 ldsB[BSLICE];   // 128 KB: this block's weight slice, swizzled
  __shared__ float h_sh[H_];
  __shared__ float red[4][16];
  __shared__ float w_sh[16];

  int bid = blockIdx.x, tid = threadIdx.x;
  int strip = bid % NSTRIP, kc = bid / NSTRIP;
  int wv = tid >> 6, lane = tid & 63;
  int lr = lane & 15, lkg = lane >> 4;

  // ---- stage this block's weight slice into LDS once (linear copy; swizzle pre-applied) ----
  {
    const uint4* src = (const uint4*)(W2ld + (size_t)bid * BSLICE);
    uint4* dst = (uint4*)ldsB;
    for (int i = tid; i < BSLICE / 8; i += 256) dst[i] = src[i];
  }
  __syncthreads();

  // per-lane LDS read bases for the 4 column sub-tiles
  int bbase[4], xm[4];
#pragma unroll
  for (int ci = 0; ci < 4; ++ci) {
    int cl = ci * 16 + lr;
    bbase[ci] = cl * 1024 + lkg * 8;
    xm[ci] = (cl & 7) * 8;
  }
  const int r0 = wv * 32;
  unsigned epoch = 0;

  for (int t = 0; t < T_; ++t) {
    // ---- phase A: partial GEMM from LDS weights ----
    {
      const _Float16* A0 = Aop + (size_t)(r0 + lr) * K3 + kc * KCH + lkg * 8;
      f32x4 acc[2][4];
#pragma unroll
      for (int ri = 0; ri < 2; ++ri)
#pragma unroll
        for (int ci = 0; ci < 4; ++ci) acc[ri][ci] = (f32x4){0.f, 0.f, 0.f, 0.f};
#pragma unroll 2
      for (int kk = 0; kk < KCH; kk += 32) {
        half8 a0 = *(const half8*)(A0 + kk);
        half8 a1 = *(const half8*)(A0 + (size_t)16 * K3 + kk);
#pragma unroll
        for (int ci = 0; ci < 4; ++ci) {
          half8 bf = *(const half8*)&ldsB[(bbase[ci] + kk) ^ xm[ci]];
          acc[0][ci] = __builtin_amdgcn_mfma_f32_16x16x32_f16(a0, bf, acc[0][ci], 0, 0, 0);
          acc[1][ci] = __builtin_amdgcn_mfma_f32_16x16x32_f16(a1, bf, acc[1][ci], 0, 0, 0);
        }
      }
      float* Pk = P + (size_t)kc * N_ * FOURH;
      int cc0 = strip * 64;
#pragma unroll
      for (int ri = 0; ri < 2; ++ri)
#pragma unroll
        for (int ci = 0; ci < 4; ++ci) {
          int col  = cc0 + 16 * ci + lr;
          int rowb = r0 + 16 * ri + lkg * 4;
#pragma unroll
          for (int j = 0; j < 4; ++j)
            Pk[(size_t)(rowb + j) * FOURH + col] = acc[ri][ci][j];
        }
    }
    ++epoch; gbar(bar, epoch * NBLOCKS);

    // ---- phase B: gates + output + next-step attention (blocks 0..127) ----
    if (bid < N_) {
      int n = bid;
      const float* P0 = P + (size_t)n * FOURH;
      const float* P1 = P0 + (size_t)N_ * FOURH;
      const float* P2 = P1 + (size_t)N_ * FOURH;
      float* cn_ptr = c + (size_t)n * H_;
      _Float16* Aopn = Aop + (size_t)n * K3;
      for (int hh = tid; hh < H_; hh += 256) {
        float ai  = P0[hh]          + P1[hh]          + P2[hh]          + b[hh];
        float af_ = P0[H_ + hh]     + P1[H_ + hh]     + P2[H_ + hh]     + b[H_ + hh];
        float ao  = P0[2 * H_ + hh] + P1[2 * H_ + hh] + P2[2 * H_ + hh] + b[2 * H_ + hh];
        float ag  = P0[3 * H_ + hh] + P1[3 * H_ + hh] + P2[3 * H_ + hh] + b[3 * H_ + hh];
        float cv = cn_ptr[hh];
        float cnew = sigf(af_) * cv + sigf(ai) * tanhf(ag);
        float hnew = sigf(ao) * tanhf(cnew);
        cn_ptr[hh] = cnew;
        out[((size_t)n * T_ + t) * H_ + hh] = hnew;
        h_sh[hh] = hnew;
        Aopn[hh] = (_Float16)hnew;
      }
      __syncthreads();
      int tn = (t + 1 < T_) ? (t + 1) : (T_ - 1);
      attn_and_x(n, tn, tid, h_sh, red, w_sh, Af16, x16, Aop);
    }
    if (t != T_ - 1) { ++epoch; gbar(bar, epoch * NBLOCKS); }
  }
}

// ---------------- launch ----------------
extern "C" void kernel_launch(void* const* d_in, const int* in_sizes, int n_in,
                              void* d_out, int out_size, void* d_ws, size_t ws_size,
                              hipStream_t stream) {
  const float* x  = (const float*)d_in[0];
  const float* A  = (const float*)d_in[1];
  const float* Wx = (const float*)d_in[2];
  const float* Wh = (const float*)d_in[3];
  const float* Wa = (const float*)d_in[4];
  const float* b  = (const float*)d_in[5];
  float* out = (float*)d_out;
  char* ws = (char*)d_ws;

  _Float16* W2ld = (_Float16*)(ws);                 // 240*65536*2 = 31,457,280
  _Float16* x16  = (_Float16*)(ws + 31457280);      // 8,388,608
  _Float16* Af16 = (_Float16*)(ws + 39845888);      // 5,242,880
  _Float16* Aop  = (_Float16*)(ws + 45088768);      // 786,432
  float*    c    = (float*)(ws + 45875200);         // 655,360
  float*    P    = (float*)(ws + 46530560);         // 7,864,320
  unsigned* bar  = (unsigned*)(ws + 54394880);      // 64
                                                    // total ~54.4 MB

  hipMemsetAsync(bar, 0, 64, stream);
  build_w2ld<<<NBLOCKS, 256, 0, stream>>>(Wh, Wa, Wx, W2ld);
  cvt_f16<<<2048, 256, 0, stream>>>(x, x16, N_ * T_ * D_);
  cvt_f16<<<2048, 256, 0, stream>>>(A, Af16, N_ * H_ * 16);
  init_state<<<N_, 256, 0, stream>>>(A, Af16, x16, c, Aop);

  const _Float16* W2ld_c = W2ld;
  const _Float16* x16_c = x16;
  const _Float16* Af16_c = Af16;
  void* args[9];
  args[0] = (void*)&W2ld_c;
  args[1] = (void*)&x16_c;
  args[2] = (void*)&Af16_c;
  args[3] = (void*)&b;
  args[4] = (void*)&c;
  args[5] = (void*)&Aop;
  args[6] = (void*)&P;
  args[7] = (void*)&out;
  args[8] = (void*)&bar;
  hipLaunchCooperativeKernel(seq_kernel, dim3(NBLOCKS), dim3(256), args, 0, stream);
}

// Round 7
// 4575.040 us; speedup vs baseline: 1.3338x; 1.3338x over previous
//
#include <hip/hip_runtime.h>

#define N_    128
#define T_    64
#define D_    512
#define H_    1280
#define FOURH 5120
#define K3    1792                 // h(1280) + x(512)
#define NSTRIP 20                  // 5120/256 col-strips (64 h-idx each)
#define NB    160                  // 20 strips x 8 batch-parts
#define SPB   16                   // samples per block
#define SCALE 0.02795084971874737f // 1/sqrt(1280)

typedef _Float16 half8 __attribute__((ext_vector_type(8)));
typedef _Float16 half2_t __attribute__((ext_vector_type(2)));
typedef float    f32x4 __attribute__((ext_vector_type(4)));
typedef unsigned u32x4 __attribute__((ext_vector_type(4)));

__device__ __forceinline__ float sigf(float x) { return 1.0f / (1.0f + __expf(-x)); }
__device__ __forceinline__ float tanhfast(float x) { return 1.0f - 2.0f / (1.0f + __expf(2.0f * x)); }

// ---- MALL-coherent access helpers ----
__device__ __forceinline__ void sc_load_u4(u32x4& d, const void* p) {
  asm volatile("global_load_dwordx4 %0, %1, off sc0 sc1" : "=v"(d) : "v"(p));
}
__device__ __forceinline__ void sc_store_u4(void* p, u32x4 d) {
  asm volatile("global_store_dwordx4 %0, %1, off sc0 sc1" :: "v"(p), "v"(d) : "memory");
}
__device__ __forceinline__ void sc_store_u1(void* p, unsigned d) {
  asm volatile("global_store_dword %0, %1, off sc0 sc1" :: "v"(p), "v"(d) : "memory");
}
__device__ __forceinline__ void vm_wait0() { asm volatile("s_waitcnt vmcnt(0)" ::: "memory"); }

// fence-free grid barrier. RELEASE = vm_wait0: every wave drains its own sc-stores
// and score atomics (vmcnt ack at MALL) BEFORE s_barrier, so thread0's relaxed
// increment truly publishes this block's data. s_barrier alone does NOT drain vmcnt
// (and the compiler cannot track inline-asm stores) — this was the r6 replay race.
__device__ __forceinline__ void gbar(unsigned* bar, unsigned target) {
  vm_wait0();
  __syncthreads();
  if (threadIdx.x == 0) {
    __hip_atomic_fetch_add(bar, 1u, __ATOMIC_RELAXED, __HIP_MEMORY_SCOPE_AGENT);
    int guard = 0;
    while (__hip_atomic_load(bar, __ATOMIC_RELAXED, __HIP_MEMORY_SCOPE_AGENT) < target &&
           ++guard < (1 << 20))
      __builtin_amdgcn_s_sleep(2);
  }
  __syncthreads();
}

// ---------------- one-time prep ----------------

// W (K x 5120 f32) -> out[colp][K] fp16, row-stride ostride, k-offset koff.
// colp = (hh>>6)*256 + (hh&63)*4 + g  (strip-major, q*4+gate interleave)
__global__ __launch_bounds__(256) void trans_w(const float* __restrict__ W,
                                               _Float16* __restrict__ out,
                                               int ostride, int koff) {
  __shared__ float tile[256][33];
  int c0 = blockIdx.x * 32, k0 = blockIdx.y * 256;
  int tx = threadIdx.x & 31, ty = threadIdx.x >> 5;
#pragma unroll
  for (int i = 0; i < 32; ++i)
    tile[ty + i * 8][tx] = W[(size_t)(k0 + ty + i * 8) * FOURH + c0 + tx];
  __syncthreads();
  int c = c0 + tx, g = c / H_, hh = c % H_;
  int colp = (hh >> 6) * 256 + (hh & 63) * 4 + g;
  _Float16* dst = out + (size_t)colp * ostride + koff + k0 + ty * 32;
#pragma unroll
  for (int i8 = 0; i8 < 4; ++i8) {
    half8 v;
#pragma unroll
    for (int j = 0; j < 8; ++j) v[j] = (_Float16)tile[ty * 32 + i8 * 8 + j][tx];
    *(half8*)(dst + i8 * 8) = v;
  }
}

// A (N,H,16 f32) -> AfT [n][l][h] fp16
__global__ __launch_bounds__(256) void prep_af(const float* __restrict__ A,
                                               _Float16* __restrict__ AfT) {
  __shared__ float tile[16][17];
  int n = blockIdx.x;
  int tl = threadIdx.x & 15, th = threadIdx.x >> 4;
  for (int hb = 0; hb < H_; hb += 16) {
    tile[th][tl] = A[((size_t)n * H_ + hb + th) * 16 + tl];
    __syncthreads();
    AfT[((size_t)n * 16 + th) * H_ + hb + tl] = (_Float16)tile[tl][th];
    __syncthreads();
  }
}

__global__ void prep_b(const float* __restrict__ b, float* __restrict__ bp) {
  int c = blockIdx.x * 256 + threadIdx.x;
  if (c < FOURH) {
    int g = c / H_, hh = c % H_;
    bp[(hh >> 6) * 256 + (hh & 63) * 4 + g] = b[c];
  }
}

// G[n][colp][l] = sum_k Wattn[k][colp] * Af[n][k][l]  (colp treated linearly, 128/block)
__global__ __launch_bounds__(256) void gemm_G(const _Float16* __restrict__ WaT,
                                              const _Float16* __restrict__ AfT,
                                              _Float16* __restrict__ G) {
  int cb = blockIdx.x;
  int wv = threadIdx.x >> 6, lane = threadIdx.x & 63, lr = lane & 15, lkg = lane >> 4;
  const _Float16* Ab = WaT + ((size_t)(cb * 128 + wv * 32 + lr)) * H_ + lkg * 8;
  for (int i = 0; i < 8; ++i) {
    int n = blockIdx.y * 8 + i;
    const _Float16* Bb = AfT + ((size_t)n * 16 + lr) * H_ + lkg * 8;
    f32x4 acc0 = (f32x4){0, 0, 0, 0}, acc1 = (f32x4){0, 0, 0, 0};
    for (int kk = 0; kk < H_; kk += 32) {
      half8 b = *(const half8*)(Bb + kk);
      half8 a0 = *(const half8*)(Ab + kk);
      half8 a1 = *(const half8*)(Ab + (size_t)16 * H_ + kk);
      acc0 = __builtin_amdgcn_mfma_f32_16x16x32_f16(a0, b, acc0, 0, 0, 0);
      acc1 = __builtin_amdgcn_mfma_f32_16x16x32_f16(a1, b, acc1, 0, 0, 0);
    }
#pragma unroll
    for (int j = 0; j < 4; ++j) {
      G[((size_t)n * FOURH + cb * 128 + wv * 32 + lkg * 4 + j) * 16 + lr] = (_Float16)acc0[j];
      G[((size_t)n * FOURH + cb * 128 + wv * 32 + 16 + lkg * 4 + j) * 16 + lr] = (_Float16)acc1[j];
    }
  }
}

// ---------------- sequential recurrence: plain launch, 160 blocks, 1 barrier/step ----------------
__global__ __launch_bounds__(256) void seq_kernel(
    const _Float16* __restrict__ Wt, const _Float16* __restrict__ G,
    const float* __restrict__ Afull, const float* __restrict__ x,
    const float* __restrict__ bp, _Float16* __restrict__ hbuf,
    float* __restrict__ S, float* __restrict__ out, unsigned* __restrict__ bar) {
  __shared__ _Float16 blds[SPB * K3];   // 57,344 B: [h|x] B-operand, XOR-swizzled
  __shared__ _Float16 htr[SPB][64];     //  2,048 B

  const int bid = blockIdx.x, tid = threadIdx.x;
  const int li = (bid & 7) * 20 + (bid >> 3);        // XCD-contiguous strip mapping
  const int s = li >> 3, rh = li & 7, n0 = rh * SPB;
  const int w = tid >> 6;
  const int lane = tid & 63, lr = lane & 15, lkg = lane >> 4, lkg8 = lkg * 8;
  const int myn = n0 + lr;
  const int bswz = (lr & 7) * 8;

  const _Float16* Arow[4];
#pragma unroll
  for (int rt = 0; rt < 4; ++rt)
    Arow[rt] = Wt + (size_t)(s * 256 + w * 64 + rt * 16 + lr) * K3 + lkg8;

  float c_reg[4];
  // ---- init: h0 = mean_l Af, c0 = h0, scores for step 0 ----
  {
    float pl[16];
#pragma unroll
    for (int l = 0; l < 16; ++l) pl[l] = 0.f;
#pragma unroll
    for (int rt = 0; rt < 4; ++rt) {
      int q = w * 16 + rt * 4 + lkg, hidx = s * 64 + q;
      const f32x4* afp = (const f32x4*)(Afull + ((size_t)myn * H_ + hidx) * 16);
      f32x4 a0 = afp[0], a1 = afp[1], a2 = afp[2], a3 = afp[3];
      float sum = 0.f;
#pragma unroll
      for (int j = 0; j < 4; ++j) sum += a0[j] + a1[j] + a2[j] + a3[j];
      float h0 = sum * 0.0625f;
      c_reg[rt] = h0;
#pragma unroll
      for (int j = 0; j < 4; ++j) {
        pl[j] += h0 * a0[j]; pl[4 + j] += h0 * a1[j];
        pl[8 + j] += h0 * a2[j]; pl[12 + j] += h0 * a3[j];
      }
      htr[lr][q] = (_Float16)h0;
    }
#pragma unroll
    for (int l = 0; l < 16; ++l) {
      pl[l] += __shfl_xor(pl[l], 16);
      pl[l] += __shfl_xor(pl[l], 32);
    }
    if (lkg == 0) {
      float* Sn = S + (size_t)myn * 16;
#pragma unroll
      for (int l = 0; l < 16; ++l)
        __hip_atomic_fetch_add(Sn + l, pl[l], __ATOMIC_RELAXED, __HIP_MEMORY_SCOPE_AGENT);
    }
    __syncthreads();
    if (tid < 128) {                        // 16 samples x 8 chunks = 64 halfs each
      int n_l = tid >> 3, hf = tid & 7;
      u32x4 v = *(const u32x4*)&htr[n_l][hf * 8];
      sc_store_u4(hbuf + ((size_t)(n0 + n_l)) * H_ + s * 64 + hf * 8, v);
    }
    gbar(bar, NB);
  }

  for (int t = 0; t < T_; ++t) {
    const int par = t & 1;
    // ---- stage h (sc) + x_t (plain) -> LDS; scores (sc) ----
    const _Float16* hsrc = hbuf + ((size_t)par * N_ + n0) * H_;
    u32x4 hv[10];
#pragma unroll
    for (int j = 0; j < 10; ++j) sc_load_u4(hv[j], hsrc + (tid + j * 256) * 8);
    u32x4 svr[4];
    const float* Sb = S + (size_t)(t % 3) * 2048 + myn * 16;
#pragma unroll
    for (int j = 0; j < 4; ++j) sc_load_u4(svr[j], Sb + j * 4);
    half8 xh[4];
#pragma unroll
    for (int j = 0; j < 4; ++j) {
      int id = tid + j * 256;
      int xn = id >> 6, d0 = (id & 63) * 8;
      const f32x4* p = (const f32x4*)(x + ((size_t)(n0 + xn) * T_ + t) * D_ + d0);
      f32x4 lo = p[0], hi = p[1];
#pragma unroll
      for (int k = 0; k < 4; ++k) { xh[j][k] = (_Float16)lo[k]; xh[j][4 + k] = (_Float16)hi[k]; }
    }
    vm_wait0();
    __builtin_amdgcn_sched_barrier(0);
#pragma unroll
    for (int j = 0; j < 10; ++j) {
      int i = tid + j * 256;
      int n_l = i / 160, c8 = i % 160;
      *(u32x4*)&blds[((size_t)n_l * 224 + (c8 ^ (n_l & 7))) * 8] = hv[j];
    }
#pragma unroll
    for (int j = 0; j < 4; ++j) {
      int id = tid + j * 256;
      int xn = id >> 6, c8 = 160 + (id & 63);
      *(half8*)&blds[((size_t)xn * 224 + (c8 ^ (xn & 7))) * 8] = xh[j];
    }
    // softmax (per-thread, 16 slots)
    float wgt[16], m = -1e30f;
#pragma unroll
    for (int j = 0; j < 4; ++j) {
      f32x4 sf = *(f32x4*)&svr[j];
#pragma unroll
      for (int k = 0; k < 4; ++k) { wgt[j * 4 + k] = sf[k] * SCALE; m = fmaxf(m, wgt[j * 4 + k]); }
    }
    float ssum = 0.f;
#pragma unroll
    for (int j = 0; j < 16; ++j) { wgt[j] = __expf(wgt[j] - m); ssum += wgt[j]; }
    float inv = 1.0f / ssum;
    half2_t wh[8];
#pragma unroll
    for (int i = 0; i < 8; ++i) {
      wh[i][0] = (_Float16)(wgt[2 * i] * inv);
      wh[i][1] = (_Float16)(wgt[2 * i + 1] * inv);
    }
    __syncthreads();

    // ---- GEMM: acc[rt] = Wcat-slice (64 gatecols x 1792) @ [h;x] (1792 x 16 samples) ----
    f32x4 acc[4];
#pragma unroll
    for (int rt = 0; rt < 4; ++rt) acc[rt] = (f32x4){0, 0, 0, 0};
#pragma unroll 4
    for (int kk = 0; kk < K3; kk += 32) {
      half8 bfrag = *(const half8*)&blds[(size_t)lr * K3 + ((kk + lkg8) ^ bswz)];
#pragma unroll
      for (int rt = 0; rt < 4; ++rt) {
        half8 a = *(const half8*)(Arow[rt] + kk);
        acc[rt] = __builtin_amdgcn_mfma_f32_16x16x32_f16(a, bfrag, acc[rt], 0, 0, 0);
      }
    }

    // ---- epilogue: gates, c/h update, out, next-step score partials ----
    float pl[16];
#pragma unroll
    for (int l = 0; l < 16; ++l) pl[l] = 0.f;
#pragma unroll
    for (int rt = 0; rt < 4; ++rt) {
      int q = w * 16 + rt * 4 + lkg, hidx = s * 64 + q, colp = s * 256 + q * 4;
      const unsigned* gp32 = (const unsigned*)(G + ((size_t)myn * FOURH + colp) * 16);
      f32x4 bb = *(const f32x4*)(bp + colp);
      float av[4];
#pragma unroll
      for (int g4 = 0; g4 < 4; ++g4) {
        float gd = 0.f;
#pragma unroll
        for (int i = 0; i < 8; ++i)
          gd = __builtin_amdgcn_fdot2(__builtin_bit_cast(half2_t, gp32[g4 * 8 + i]), wh[i], gd, false);
        av[g4] = acc[rt][g4] + gd + bb[g4];
      }
      float cn = sigf(av[1]) * c_reg[rt] + sigf(av[0]) * tanhfast(av[3]);
      c_reg[rt] = cn;
      float hn = sigf(av[2]) * tanhfast(cn);
      out[((size_t)myn * T_ + t) * H_ + hidx] = hn;
      if (t < T_ - 1) {
        const f32x4* afp = (const f32x4*)(Afull + ((size_t)myn * H_ + hidx) * 16);
        f32x4 a0 = afp[0], a1 = afp[1], a2 = afp[2], a3 = afp[3];
#pragma unroll
        for (int j = 0; j < 4; ++j) {
          pl[j] += hn * a0[j]; pl[4 + j] += hn * a1[j];
          pl[8 + j] += hn * a2[j]; pl[12 + j] += hn * a3[j];
        }
        htr[lr][q] = (_Float16)hn;
      }
    }
    if (t < T_ - 1) {
#pragma unroll
      for (int l = 0; l < 16; ++l) {
        pl[l] += __shfl_xor(pl[l], 16);
        pl[l] += __shfl_xor(pl[l], 32);
      }
      if (lkg == 0) {
        float* Sn = S + (size_t)((t + 1) % 3) * 2048 + myn * 16;
#pragma unroll
        for (int l = 0; l < 16; ++l)
          __hip_atomic_fetch_add(Sn + l, pl[l], __ATOMIC_RELAXED, __HIP_MEMORY_SCOPE_AGENT);
      }
      if (bid < 64 && tid < 32)   // zero exactly 2048 words of S[(t+2)%3]
        sc_store_u1((unsigned*)(S + (size_t)((t + 2) % 3) * 2048) + bid * 32 + tid, 0u);
      __syncthreads();
      if (tid < 128) {
        int n_l = tid >> 3, hf = tid & 7;
        u32x4 v = *(const u32x4*)&htr[n_l][hf * 8];
        sc_store_u4(hbuf + ((size_t)((par ^ 1) * N_) + n0 + n_l) * H_ + s * 64 + hf * 8, v);
      }
      gbar(bar, (unsigned)(t + 2) * NB);
    }
  }
}

// ---------------- launch ----------------
extern "C" void kernel_launch(void* const* d_in, const int* in_sizes, int n_in,
                              void* d_out, int out_size, void* d_ws, size_t ws_size,
                              hipStream_t stream) {
  const float* x  = (const float*)d_in[0];
  const float* A  = (const float*)d_in[1];
  const float* Wx = (const float*)d_in[2];
  const float* Wh = (const float*)d_in[3];
  const float* Wa = (const float*)d_in[4];
  const float* b  = (const float*)d_in[5];
  float* out = (float*)d_out;
  char* ws = (char*)d_ws;

  _Float16* Xreg = (_Float16*)(ws);                 // 18,350,080 (WaT, then WcatT)
  _Float16* AfT  = (_Float16*)(ws + 18350080);      //  5,242,880
  _Float16* G    = (_Float16*)(ws + 23592960);      // 20,971,520
  _Float16* hbuf = (_Float16*)(ws + 44564480);      //    655,360
  float*    S    = (float*)(ws + 45219840);         //     24,576 (3 x 128 x 16)
  unsigned* bar  = (unsigned*)(ws + 45244416);      //         64
  float*    bpm  = (float*)(ws + 45244480);         //     20,480  -> total 45.3 MB

  (void)hipMemsetAsync(S, 0, 24576 + 64, stream);   // S + bar
  // phase 1: WaT into Xreg, G = Af^T @ Wattn
  trans_w<<<dim3(160, 5), 256, 0, stream>>>(Wa, Xreg, H_, 0);
  prep_af<<<N_, 256, 0, stream>>>(A, AfT);
  gemm_G<<<dim3(40, 16), 256, 0, stream>>>(Xreg, AfT, G);
  // phase 2: overwrite Xreg with WcatT = [Wh; Wx] (K-major, stride 1792)
  trans_w<<<dim3(160, 5), 256, 0, stream>>>(Wh, Xreg, K3, 0);
  trans_w<<<dim3(160, 2), 256, 0, stream>>>(Wx, Xreg, K3, H_);
  prep_b<<<20, 256, 0, stream>>>(b, bpm);

  seq_kernel<<<dim3(NB), dim3(256), 0, stream>>>(Xreg, G, A, x, bpm, hbuf, S, out, bar);
}

// Round 9
// 2277.636 us; speedup vs baseline: 2.6791x; 2.0087x over previous
//
#include <hip/hip_runtime.h>

#define N_    128
#define T_    64
#define D_    512
#define H_    1280
#define FOURH 5120
#define K3    1792                 // h(1280) + x(512)
#define COLS  160                  // gate-cols per strip (40 q x 4 gates)
#define ACCS  165                  // padded acclds row stride (f32) — kills 16-way bank conflict
#define NB    256                  // 32 strips x 8 rh
#define SPB   16                   // samples per block
#define SCALE 0.02795084971874737f // 1/sqrt(1280)

typedef _Float16 half8 __attribute__((ext_vector_type(8)));
typedef _Float16 half2_t __attribute__((ext_vector_type(2)));
typedef float    f32x4 __attribute__((ext_vector_type(4)));
typedef unsigned u32x4 __attribute__((ext_vector_type(4)));

__device__ __forceinline__ float sigf(float x) { return 1.0f / (1.0f + __expf(-x)); }
__device__ __forceinline__ float tanhfast(float x) { return 1.0f - 2.0f / (1.0f + __expf(2.0f * x)); }

__device__ __forceinline__ void sc_load_u4(u32x4& d, const void* p) {
  asm volatile("global_load_dwordx4 %0, %1, off sc0 sc1" : "=v"(d) : "v"(p));
}
__device__ __forceinline__ void sc_store_u4(void* p, u32x4 d) {
  asm volatile("global_store_dwordx4 %0, %1, off sc0 sc1" :: "v"(p), "v"(d) : "memory");
}
__device__ __forceinline__ void sc_store_u1(void* p, unsigned d) {
  asm volatile("global_store_dword %0, %1, off sc0 sc1" :: "v"(p), "v"(d) : "memory");
}
__device__ __forceinline__ void vm_wait0() { asm volatile("s_waitcnt vmcnt(0)" ::: "memory"); }

// fence-free grid barrier; release = vm_wait0 (drains sc-stores + atomics to MALL)
__device__ __forceinline__ void gbar(unsigned* bar, unsigned target) {
  vm_wait0();
  __syncthreads();
  if (threadIdx.x == 0) {
    __hip_atomic_fetch_add(bar, 1u, __ATOMIC_RELAXED, __HIP_MEMORY_SCOPE_AGENT);
    int guard = 0;
    while (__hip_atomic_load(bar, __ATOMIC_RELAXED, __HIP_MEMORY_SCOPE_AGENT) < target &&
           ++guard < (1 << 20))
      __builtin_amdgcn_s_sleep(2);
  }
  __syncthreads();
}

// ---------------- one-time prep ----------------

// W (K x 5120 f32) -> out[colp][K] fp16. colp = (hh/40)*160 + (hh%40)*4 + g
__global__ __launch_bounds__(256) void trans_w(const float* __restrict__ W,
                                               _Float16* __restrict__ out,
                                               int ostride, int koff) {
  __shared__ float tile[256][33];
  int c0 = blockIdx.x * 32, k0 = blockIdx.y * 256;
  int tx = threadIdx.x & 31, ty = threadIdx.x >> 5;
#pragma unroll
  for (int i = 0; i < 32; ++i)
    tile[ty + i * 8][tx] = W[(size_t)(k0 + ty + i * 8) * FOURH + c0 + tx];
  __syncthreads();
  int c = c0 + tx, g = c / H_, hh = c % H_;
  int colp = (hh / 40) * COLS + (hh % 40) * 4 + g;
  _Float16* dst = out + (size_t)colp * ostride + koff + k0 + ty * 32;
#pragma unroll
  for (int i8 = 0; i8 < 4; ++i8) {
    half8 v;
#pragma unroll
    for (int j = 0; j < 8; ++j) v[j] = (_Float16)tile[ty * 32 + i8 * 8 + j][tx];
    *(half8*)(dst + i8 * 8) = v;
  }
}

__global__ __launch_bounds__(256) void cvt_f16(const float* __restrict__ src,
                                               _Float16* __restrict__ dst, int n) {
  for (int i = blockIdx.x * blockDim.x + threadIdx.x; i < n; i += gridDim.x * blockDim.x)
    dst[i] = (_Float16)src[i];
}

// A (N,H,16 f32) -> AfT [n][l][h] fp16 (for gemm_G) and Af16 [n][h][l] fp16 (epilogue)
__global__ __launch_bounds__(256) void prep_af(const float* __restrict__ A,
                                               _Float16* __restrict__ AfT,
                                               _Float16* __restrict__ Af16) {
  __shared__ float tile[16][17];
  int n = blockIdx.x;
  int tl = threadIdx.x & 15, th = threadIdx.x >> 4;
  for (int hb = 0; hb < H_; hb += 16) {
    float v = A[((size_t)n * H_ + hb + th) * 16 + tl];
    Af16[((size_t)n * H_ + hb + th) * 16 + tl] = (_Float16)v;
    tile[th][tl] = v;
    __syncthreads();
    AfT[((size_t)n * 16 + th) * H_ + hb + tl] = (_Float16)tile[tl][th];
    __syncthreads();
  }
}

__global__ void prep_b(const float* __restrict__ b, float* __restrict__ bp) {
  int c = blockIdx.x * 256 + threadIdx.x;
  if (c < FOURH) {
    int g = c / H_, hh = c % H_;
    bp[(hh / 40) * COLS + (hh % 40) * 4 + g] = b[c];
  }
}

// G[n][colp][l] = sum_k Wattn[k][colp] * Af[n][k][l]
__global__ __launch_bounds__(256) void gemm_G(const _Float16* __restrict__ WaT,
                                              const _Float16* __restrict__ AfT,
                                              _Float16* __restrict__ G) {
  int cb = blockIdx.x;
  int wv = threadIdx.x >> 6, lane = threadIdx.x & 63, lr = lane & 15, lkg = lane >> 4;
  const _Float16* Ab = WaT + ((size_t)(cb * 128 + wv * 32 + lr)) * H_ + lkg * 8;
  for (int i = 0; i < 8; ++i) {
    int n = blockIdx.y * 8 + i;
    const _Float16* Bb = AfT + ((size_t)n * 16 + lr) * H_ + lkg * 8;
    f32x4 acc0 = (f32x4){0, 0, 0, 0}, acc1 = (f32x4){0, 0, 0, 0};
    for (int kk = 0; kk < H_; kk += 32) {
      half8 b = *(const half8*)(Bb + kk);
      half8 a0 = *(const half8*)(Ab + kk);
      half8 a1 = *(const half8*)(Ab + (size_t)16 * H_ + kk);
      acc0 = __builtin_amdgcn_mfma_f32_16x16x32_f16(a0, b, acc0, 0, 0, 0);
      acc1 = __builtin_amdgcn_mfma_f32_16x16x32_f16(a1, b, acc1, 0, 0, 0);
    }
#pragma unroll
    for (int j = 0; j < 4; ++j) {
      G[((size_t)n * FOURH + cb * 128 + wv * 32 + lkg * 4 + j) * 16 + lr] = (_Float16)acc0[j];
      G[((size_t)n * FOURH + cb * 128 + wv * 32 + 16 + lkg * 4 + j) * 16 + lr] = (_Float16)acc1[j];
    }
  }
}

// ---------------- sequential recurrence: 256 blocks x 640 threads, 1 barrier/step ----------------
__global__ __launch_bounds__(640, 3) void seq_kernel(
    const _Float16* __restrict__ Wt, const _Float16* __restrict__ G,
    const float* __restrict__ Afull, const _Float16* __restrict__ Af16,
    const _Float16* __restrict__ x16, const float* __restrict__ bp,
    _Float16* __restrict__ hbuf, float* __restrict__ S,
    float* __restrict__ out, unsigned* __restrict__ bar) {
  __shared__ _Float16 blds[SPB * K3];        // 57,344 B  (aliased as acc f32[16][ACCS] post-GEMM)
  __shared__ _Float16 glds[SPB * COLS * 16]; // 81,920 B  (G slice, loaded once)
  __shared__ _Float16 htr[SPB][40];          //  1,280 B
  __shared__ float sred[10][16][17];         // 10,880 B  (padded: 8-way conflict fix)
  __shared__ float sc_s[16][16];             //  1,024 B
  float* acclds = (float*)blds;

  const int bid = blockIdx.x, tid = threadIdx.x;
  const int li = (bid & 7) * 32 + (bid >> 3);   // cluster strips per XCD
  const int s = li >> 3, rh = li & 7, n0 = rh * SPB;
  const int w = tid >> 6, lane = tid & 63;
  const int lr = lane & 15, lkg = lane >> 4, lkg8 = lkg * 8;
  const int bswz = (lr & 7) * 8;
  const int en = tid & 15, eq = tid >> 4;       // epilogue: thread owns (sample en, q eq)
  const int ehidx = s * 40 + eq;
  const int emyn = n0 + en;

  // ---- G slice -> LDS once (step-invariant): 16n x 160colp x 16l ----
#pragma unroll
  for (int j = 0; j < 8; ++j) {
    int id = tid + j * 640;
    if (id < 5120) {
      int n = id / 320, r = id % 320;
      *(u32x4*)&glds[n * 2560 + r * 8] =
          *(const u32x4*)(G + ((size_t)(n0 + n) * FOURH + s * COLS) * 16 + r * 8);
    }
  }

  const _Float16* Ap = Wt + (size_t)(s * COLS + w * 16 + lr) * K3 + lkg8;
  float c_reg;

  // ---- init: h0 = mean_l Af, c0 = h0, scores for step 0 ----
  {
    const f32x4* afp = (const f32x4*)(Afull + ((size_t)emyn * H_ + ehidx) * 16);
    f32x4 a0 = afp[0], a1 = afp[1], a2 = afp[2], a3 = afp[3];
    float sum = 0.f;
#pragma unroll
    for (int j = 0; j < 4; ++j) sum += a0[j] + a1[j] + a2[j] + a3[j];
    float h0 = sum * 0.0625f;
    c_reg = h0;
    htr[en][eq] = (_Float16)h0;
    float pl[16];
#pragma unroll
    for (int j = 0; j < 4; ++j) {
      pl[j] = h0 * a0[j]; pl[4 + j] = h0 * a1[j];
      pl[8 + j] = h0 * a2[j]; pl[12 + j] = h0 * a3[j];
    }
#pragma unroll
    for (int l = 0; l < 16; ++l) {
      pl[l] += __shfl_xor(pl[l], 16);
      pl[l] += __shfl_xor(pl[l], 32);
    }
    if (lane < 16) {
#pragma unroll
      for (int l = 0; l < 16; ++l) sred[w][lane][l] = pl[l];
    }
    __syncthreads();
    if (tid < 256) {
      int n = tid >> 4, l = tid & 15;
      float v = 0.f;
#pragma unroll
      for (int ww = 0; ww < 10; ++ww) v += sred[ww][n][l];
      __hip_atomic_fetch_add(S + (size_t)(n0 + n) * 16 + l, v,
                             __ATOMIC_RELAXED, __HIP_MEMORY_SCOPE_AGENT);
    }
    if (tid < 80) {
      int n = tid / 5, ch = tid % 5;
      u32x4 v = *(const u32x4*)&htr[n][ch * 8];
      sc_store_u4(hbuf + (size_t)(n0 + n) * H_ + s * 40 + ch * 8, v);
    }
    gbar(bar, NB);
  }

  for (int t = 0; t < T_; ++t) {
    const int par = t & 1;
    // ---- stage h (sc) + x_t -> LDS; scores (sc) via LDS ----
    const _Float16* hsrc = hbuf + ((size_t)par * N_ + n0) * H_;
    u32x4 hv[4];
#pragma unroll
    for (int j = 0; j < 4; ++j) sc_load_u4(hv[j], hsrc + (tid + j * 640) * 8);
    u32x4 svr;
    if (tid < 64)
      sc_load_u4(svr, S + (size_t)(t % 3) * 2048 + (size_t)(n0 + (tid >> 2)) * 16 + (tid & 3) * 4);
    half8 xh[2];
#pragma unroll
    for (int j = 0; j < 2; ++j) {
      int id = tid + j * 640;
      if (id < 1024)
        xh[j] = *(const half8*)(x16 + ((size_t)(n0 + (id >> 6)) * T_ + t) * D_ + (id & 63) * 8);
    }
    vm_wait0();
    __builtin_amdgcn_sched_barrier(0);
#pragma unroll
    for (int j = 0; j < 4; ++j) {
      int i = tid + j * 640;
      int n_l = i / 160, c8 = i % 160;
      *(u32x4*)&blds[((size_t)n_l * 224 + (c8 ^ (n_l & 7))) * 8] = hv[j];
    }
#pragma unroll
    for (int j = 0; j < 2; ++j) {
      int id = tid + j * 640;
      if (id < 1024) {
        int xn = id >> 6, c8 = 160 + (id & 63);
        *(half8*)&blds[((size_t)xn * 224 + (c8 ^ (xn & 7))) * 8] = xh[j];
      }
    }
    if (tid < 64) *(u32x4*)&sc_s[tid >> 2][(tid & 3) * 4] = svr;
    __syncthreads();

    // softmax for this thread's sample
    float wgt[16], m = -1e30f;
#pragma unroll
    for (int l = 0; l < 16; ++l) { wgt[l] = sc_s[en][l] * SCALE; m = fmaxf(m, wgt[l]); }
    float ssum = 0.f;
#pragma unroll
    for (int l = 0; l < 16; ++l) { wgt[l] = __expf(wgt[l] - m); ssum += wgt[l]; }
    float inv = 1.0f / ssum;
    half2_t wh[8];
#pragma unroll
    for (int i = 0; i < 8; ++i) {
      wh[i][0] = (_Float16)(wgt[2 * i] * inv);
      wh[i][1] = (_Float16)(wgt[2 * i + 1] * inv);
    }

    // ---- GEMM: wave w owns 16 cols; depth-8 A double-buffer from L2-resident W ----
    f32x4 acc = (f32x4){0, 0, 0, 0};
    {
      half8 a0[4], a1[4];
#pragma unroll
      for (int j = 0; j < 4; ++j) a0[j] = *(const half8*)(Ap + j * 32);
#pragma unroll
      for (int rep = 0; rep < 6; ++rep) {
        const int base = rep * 256;
#pragma unroll
        for (int j = 0; j < 4; ++j) a1[j] = *(const half8*)(Ap + base + 128 + j * 32);
#pragma unroll
        for (int j = 0; j < 4; ++j) {
          half8 bf = *(const half8*)&blds[(size_t)lr * K3 + ((base + j * 32 + lkg8) ^ bswz)];
          acc = __builtin_amdgcn_mfma_f32_16x16x32_f16(a0[j], bf, acc, 0, 0, 0);
        }
#pragma unroll
        for (int j = 0; j < 4; ++j) a0[j] = *(const half8*)(Ap + base + 256 + j * 32);
#pragma unroll
        for (int j = 0; j < 4; ++j) {
          half8 bf = *(const half8*)&blds[(size_t)lr * K3 + ((base + 128 + j * 32 + lkg8) ^ bswz)];
          acc = __builtin_amdgcn_mfma_f32_16x16x32_f16(a1[j], bf, acc, 0, 0, 0);
        }
      }
#pragma unroll
      for (int j = 0; j < 4; ++j) a1[j] = *(const half8*)(Ap + 1664 + j * 32);
#pragma unroll
      for (int j = 0; j < 4; ++j) {
        half8 bf = *(const half8*)&blds[(size_t)lr * K3 + ((1536 + j * 32 + lkg8) ^ bswz)];
        acc = __builtin_amdgcn_mfma_f32_16x16x32_f16(a0[j], bf, acc, 0, 0, 0);
      }
#pragma unroll
      for (int j = 0; j < 4; ++j) {
        half8 bf = *(const half8*)&blds[(size_t)lr * K3 + ((1664 + j * 32 + lkg8) ^ bswz)];
        acc = __builtin_amdgcn_mfma_f32_16x16x32_f16(a1[j], bf, acc, 0, 0, 0);
      }
    }
    __syncthreads();                       // B consumed; alias blds as acc transpose
    // D[row=(lkg*4+j)=gatecol_local, col=lr=sample] -> acclds[sample][gatecol]
    // (r8 bug: indices were swapped -> gates scrambled across samples)
#pragma unroll
    for (int j = 0; j < 4; ++j)
      acclds[lr * ACCS + w * 16 + lkg * 4 + j] = acc[j];
    __syncthreads();

    // ---- epilogue: thread (en, eq) -> 4 gates, c/h update, out, score partials ----
    {
      const float* av4 = acclds + en * ACCS + eq * 4;
      const unsigned* gp32 = (const unsigned*)(glds + en * 2560 + eq * 64);
      f32x4 bb = *(const f32x4*)(bp + s * COLS + eq * 4);
      float av[4];
#pragma unroll
      for (int g4 = 0; g4 < 4; ++g4) {
        float gd = 0.f;
#pragma unroll
        for (int i = 0; i < 8; ++i)
          gd = __builtin_amdgcn_fdot2(__builtin_bit_cast(half2_t, gp32[g4 * 8 + i]), wh[i], gd, false);
        av[g4] = av4[g4] + gd + bb[g4];
      }
      float cn = sigf(av[1]) * c_reg + sigf(av[0]) * tanhfast(av[3]);
      c_reg = cn;
      float hn = sigf(av[2]) * tanhfast(cn);
      out[((size_t)emyn * T_ + t) * H_ + ehidx] = hn;

      if (t < T_ - 1) {
        const half8* af8 = (const half8*)(Af16 + ((size_t)emyn * H_ + ehidx) * 16);
        half8 v0 = af8[0], v1 = af8[1];
        float pl[16];
#pragma unroll
        for (int l = 0; l < 8; ++l) { pl[l] = hn * (float)v0[l]; pl[8 + l] = hn * (float)v1[l]; }
        htr[en][eq] = (_Float16)hn;
#pragma unroll
        for (int l = 0; l < 16; ++l) {
          pl[l] += __shfl_xor(pl[l], 16);
          pl[l] += __shfl_xor(pl[l], 32);
        }
        if (lane < 16) {
#pragma unroll
          for (int l = 0; l < 16; ++l) sred[w][lane][l] = pl[l];
        }
        __syncthreads();
        if (tid < 256) {
          int n = tid >> 4, l = tid & 15;
          float v = 0.f;
#pragma unroll
          for (int ww = 0; ww < 10; ++ww) v += sred[ww][n][l];
          __hip_atomic_fetch_add(S + (size_t)((t + 1) % 3) * 2048 + (size_t)(n0 + n) * 16 + l, v,
                                 __ATOMIC_RELAXED, __HIP_MEMORY_SCOPE_AGENT);
        }
        if (bid < 64 && tid < 32)   // zero exactly 2048 words of S[(t+2)%3]
          sc_store_u1((unsigned*)(S + (size_t)((t + 2) % 3) * 2048) + bid * 32 + tid, 0u);
        if (tid < 80) {
          int n = tid / 5, ch = tid % 5;
          u32x4 v = *(const u32x4*)&htr[n][ch * 8];
          sc_store_u4(hbuf + ((size_t)((par ^ 1) * N_) + n0 + n) * H_ + s * 40 + ch * 8, v);
        }
        gbar(bar, (unsigned)(t + 2) * NB);
      }
    }
  }
}

// ---------------- launch ----------------
extern "C" void kernel_launch(void* const* d_in, const int* in_sizes, int n_in,
                              void* d_out, int out_size, void* d_ws, size_t ws_size,
                              hipStream_t stream) {
  const float* x  = (const float*)d_in[0];
  const float* A  = (const float*)d_in[1];
  const float* Wx = (const float*)d_in[2];
  const float* Wh = (const float*)d_in[3];
  const float* Wa = (const float*)d_in[4];
  const float* b  = (const float*)d_in[5];
  float* out = (float*)d_out;
  char* ws = (char*)d_ws;

  _Float16* Xreg = (_Float16*)(ws);                 // 18,350,080 (WaT then WcatT)
  _Float16* x16r = (_Float16*)(ws + 18350080);      //  8,388,608 (first holds AfT 5,242,880)
  _Float16* G    = (_Float16*)(ws + 26738688);      // 20,971,520
  _Float16* Af16 = (_Float16*)(ws + 47710208);      //  5,242,880
  _Float16* hbuf = (_Float16*)(ws + 52953088);      //    655,360
  float*    S    = (float*)(ws + 53608448);         //     24,576
  unsigned* bar  = (unsigned*)(ws + 53633024);      //         64
  float*    bpm  = (float*)(ws + 53633088);         //     20,480  -> total 53.65 MB

  (void)hipMemsetAsync(S, 0, 24576 + 64, stream);   // S + bar
  // phase 1: WaT into Xreg; AfT into x16 region; G = Af^T @ Wattn
  trans_w<<<dim3(160, 5), 256, 0, stream>>>(Wa, Xreg, H_, 0);
  prep_af<<<N_, 256, 0, stream>>>(A, x16r, Af16);
  gemm_G<<<dim3(40, 16), 256, 0, stream>>>(Xreg, x16r, G);
  // phase 2: overwrite Xreg with WcatT = [Wh; Wx]; overwrite AfT region with x16
  trans_w<<<dim3(160, 5), 256, 0, stream>>>(Wh, Xreg, K3, 0);
  trans_w<<<dim3(160, 2), 256, 0, stream>>>(Wx, Xreg, K3, H_);
  cvt_f16<<<2048, 256, 0, stream>>>(x, x16r, N_ * T_ * D_);
  prep_b<<<20, 256, 0, stream>>>(b, bpm);

  seq_kernel<<<dim3(NB), dim3(640), 0, stream>>>(Xreg, G, A, Af16, x16r, bpm, hbuf, S, out, bar);
}